// Round 3
// baseline (654.173 us; speedup 1.0000x reference)
//
#include <hip/hip_runtime.h>

#define D 64
#define SCAN_CHUNK 1024

// ---------------- rel kernel: R = rel_emb @ Wf^T ; rel_out = rel_emb @ Wrel^T
// W staged transposed in LDS: Wt[k][j] -> lane j reads bank j%32, 2-way = free.
__global__ __launch_bounds__(256) void rel_kernel(
    const float* __restrict__ rel_emb,
    const float* __restrict__ W_f,
    const float* __restrict__ W_rel,
    float* __restrict__ R,
    float* __restrict__ rel_out,
    int n_rel) {
  __shared__ float WtF[D][D];
  __shared__ float WtR[D][D];
  int tid = threadIdx.x;
  for (int idx = tid; idx < D * D; idx += 256) {
    int j = idx >> 6, k = idx & 63;
    WtF[k][j] = W_f[idx];
    WtR[k][j] = W_rel[idx];
  }
  __syncthreads();
  int lane = tid & 63, wave = tid >> 6;
  for (int r = blockIdx.x * 4 + wave; r < n_rel; r += gridDim.x * 4) {
    const float4* a = (const float4*)(rel_emb + (size_t)r * D);
    float accR = 0.f, accO = 0.f;
#pragma unroll
    for (int k4 = 0; k4 < 16; ++k4) {
      float4 av = a[k4];
      int k = k4 * 4;
      accR += av.x * WtF[k][lane] + av.y * WtF[k + 1][lane] +
              av.z * WtF[k + 2][lane] + av.w * WtF[k + 3][lane];
      accO += av.x * WtR[k][lane] + av.y * WtR[k + 1][lane] +
              av.z * WtR[k + 2][lane] + av.w * WtR[k + 3][lane];
    }
    R[(size_t)r * D + lane] = accR;
    rel_out[(size_t)r * D + lane] = accO;
  }
}

// ---------------- node matmul: dst = nf @ W^T (+ bias). Lane j holds W row j.
__global__ __launch_bounds__(256, 4) void node_mm(
    const float* __restrict__ nf, const float* __restrict__ W,
    const float* __restrict__ bias, float* __restrict__ dst, int n_nodes) {
  int lane = threadIdx.x & 63;
  float4 w[16];
  const float4* Wv = (const float4*)(W + lane * D);
#pragma unroll
  for (int k = 0; k < 16; ++k) w[k] = Wv[k];
  float b = bias ? bias[lane] : 0.f;

  int wave_id = (int)((blockIdx.x * blockDim.x + threadIdx.x) >> 6);
  int n_waves = (int)((gridDim.x * blockDim.x) >> 6);
  for (int row = wave_id; row < n_nodes; row += n_waves) {
    const float4* a = (const float4*)(nf + (size_t)row * D);
    float acc = b;
#pragma unroll 8
    for (int k = 0; k < 16; ++k) {
      float4 av = a[k];  // wave-uniform address -> broadcast
      acc += av.x * w[k].x + av.y * w[k].y + av.z * w[k].z + av.w * w[k].w;
    }
    dst[(size_t)row * D + lane] = acc;
  }
}

// ---------------- CSR build ----------------
__global__ __launch_bounds__(256) void k_zero(int* __restrict__ p, int n) {
  int i = blockIdx.x * blockDim.x + threadIdx.x;
  int stride = gridDim.x * blockDim.x;
  for (; i < n; i += stride) p[i] = 0;
}

__global__ __launch_bounds__(256) void k_hist(
    const int* __restrict__ dst, const int* __restrict__ dir,
    int* __restrict__ cnt, int n_edges) {
  int i = blockIdx.x * blockDim.x + threadIdx.x;
  int stride = gridDim.x * blockDim.x;
  for (; i < n_edges; i += stride)
    if (dir[i] == 0) atomicAdd(&cnt[dst[i]], 1);
}

// per-chunk sums
__global__ __launch_bounds__(256) void k_sums(
    const int* __restrict__ cnt, int* __restrict__ sums, int n) {
  __shared__ int ws_[4];
  int b = blockIdx.x, t = threadIdx.x;
  int lane = t & 63, wave = t >> 6;
  int s = 0;
  for (int j = 0; j < 4; ++j) {
    int i = b * SCAN_CHUNK + t * 4 + j;
    if (i < n) s += cnt[i];
  }
  for (int off = 32; off; off >>= 1) s += __shfl_down(s, off);
  if (lane == 0) ws_[wave] = s;
  __syncthreads();
  if (t == 0) sums[b] = ws_[0] + ws_[1] + ws_[2] + ws_[3];
}

// exclusive scan of block sums (nblk <= 1024), single block of 1024 threads
__global__ __launch_bounds__(1024) void k_scan_sums(int* __restrict__ sums, int nblk) {
  __shared__ int l[1024];
  int t = threadIdx.x;
  l[t] = (t < nblk) ? sums[t] : 0;
  __syncthreads();
  for (int d = 1; d < 1024; d <<= 1) {
    int v = (t >= d) ? l[t - d] : 0;
    __syncthreads();
    l[t] += v;
    __syncthreads();
  }
  if (t < nblk) sums[t] = (t == 0) ? 0 : l[t - 1];
}

// in-place: cnt chunk -> exclusive prefix (+ chunk base)
__global__ __launch_bounds__(256) void k_scan_chunks(
    int* __restrict__ cnt, const int* __restrict__ sums, int n) {
  __shared__ int wsum[4];
  int b = blockIdx.x, t = threadIdx.x;
  int lane = t & 63, wave = t >> 6;
  int i0 = b * SCAN_CHUNK + t * 4;
  int c0 = (i0 + 0 < n) ? cnt[i0 + 0] : 0;
  int c1 = (i0 + 1 < n) ? cnt[i0 + 1] : 0;
  int c2 = (i0 + 2 < n) ? cnt[i0 + 2] : 0;
  int c3 = (i0 + 3 < n) ? cnt[i0 + 3] : 0;
  int s = c0 + c1 + c2 + c3;
  int inc = s;
  for (int d = 1; d < 64; d <<= 1) {
    int v = __shfl_up(inc, d);
    if (lane >= d) inc += v;
  }
  if (lane == 63) wsum[wave] = inc;
  __syncthreads();
  int wbase = 0;
  if (wave > 0) wbase += wsum[0];
  if (wave > 1) wbase += wsum[1];
  if (wave > 2) wbase += wsum[2];
  int ex = sums[b] + wbase + inc - s;
  if (i0 + 0 < n) cnt[i0 + 0] = ex;
  if (i0 + 1 < n) cnt[i0 + 1] = ex + c0;
  if (i0 + 2 < n) cnt[i0 + 2] = ex + c0 + c1;
  if (i0 + 3 < n) cnt[i0 + 3] = ex + c0 + c1 + c2;
}

__global__ __launch_bounds__(256) void k_scatter(
    const int* __restrict__ dst, const int* __restrict__ dir,
    int* __restrict__ cursor, int* __restrict__ perm, int n_edges) {
  int i = blockIdx.x * blockDim.x + threadIdx.x;
  int stride = gridDim.x * blockDim.x;
  for (; i < n_edges; i += stride)
    if (dir[i] == 0) {
      int pos = atomicAdd(&cursor[dst[i]], 1);
      perm[pos] = i;
    }
}

// ---------------- gather: out[n] += sum_{e in bucket(n)} X[src[e]] - R[et[e]]
__global__ __launch_bounds__(256) void k_gather(
    const int* __restrict__ cursor, const int* __restrict__ perm,
    const int* __restrict__ src, const int* __restrict__ etype,
    const float* __restrict__ X, const float* __restrict__ R,
    float* __restrict__ out, int n_nodes) {
  int lane = threadIdx.x & 63;
  int wave_id = (int)((blockIdx.x * blockDim.x + threadIdx.x) >> 6);
  int n_waves = (int)((gridDim.x * blockDim.x) >> 6);
  for (int node = wave_id; node < n_nodes; node += n_waves) {
    int end = cursor[node];                       // post-scatter: bucket end
    int beg = (node == 0) ? 0 : cursor[node - 1]; // = bucket start
    if (end <= beg) continue;
    float acc = 0.f;
    int k = beg;
    for (; k + 1 < end; k += 2) {  // dual-edge for MLP
      int e0 = perm[k], e1 = perm[k + 1];
      int s0 = src[e0], t0 = etype[e0];
      int s1 = src[e1], t1 = etype[e1];
      float a0 = X[(size_t)s0 * D + lane] - R[(size_t)t0 * D + lane];
      float a1 = X[(size_t)s1 * D + lane] - R[(size_t)t1 * D + lane];
      acc += a0 + a1;
    }
    if (k < end) {
      int e0 = perm[k];
      acc += X[(size_t)src[e0] * D + lane] - R[(size_t)etype[e0] * D + lane];
    }
    out[(size_t)node * D + lane] += acc;
  }
}

// ---------------- fallback edge kernel (proven R1 version) ----------------
__global__ __launch_bounds__(256) void edge_atomic(
    const int* __restrict__ src, const int* __restrict__ dst,
    const int* __restrict__ et, const int* __restrict__ dir,
    const float* __restrict__ X, const float* __restrict__ R,
    float* __restrict__ out, int n_edges) {
  int lane = threadIdx.x & 63;
  long long wave_id = ((long long)blockIdx.x * blockDim.x + threadIdx.x) >> 6;
  long long n_waves = ((long long)gridDim.x * blockDim.x) >> 6;
  for (long long base = wave_id * 64; base < n_edges; base += n_waves * 64) {
    int e = (int)base + lane;
    int s_l = 0, d_l = 0, t_l = 0, dir_l = 1;
    if (e < n_edges) {
      s_l = src[e]; d_l = dst[e]; t_l = et[e]; dir_l = dir[e];
    }
    int cnt = min(64, n_edges - (int)base);
    for (int i = 0; i < cnt; ++i) {
      int dir_i = __shfl(dir_l, i);
      if (dir_i != 0) continue;
      int s_i = __shfl(s_l, i);
      int t_i = __shfl(t_l, i);
      int d_i = __shfl(d_l, i);
      float val = X[(size_t)s_i * D + lane] - R[(size_t)t_i * D + lane];
      atomicAdd(&out[(size_t)d_i * D + lane], val);
    }
  }
}

extern "C" void kernel_launch(void* const* d_in, const int* in_sizes, int n_in,
                              void* d_out, int out_size, void* d_ws, size_t ws_size,
                              hipStream_t stream) {
  const float* node_feat = (const float*)d_in[0];
  const float* rel_emb   = (const float*)d_in[1];
  const int*   src       = (const int*)d_in[2];
  const int*   dst       = (const int*)d_in[3];
  const int*   etype     = (const int*)d_in[4];
  const int*   direction = (const int*)d_in[5];
  const float* W_self    = (const float*)d_in[6];
  const float* W_forward = (const float*)d_in[7];
  // d_in[8] = W_backward (unused: backward edges contribute zero)
  const float* W_rel     = (const float*)d_in[9];
  const float* bias      = (const float*)d_in[10];

  int n_nodes = in_sizes[0] / D;
  int n_rel   = in_sizes[1] / D;
  int n_edges = in_sizes[2];

  float* out     = (float*)d_out;
  float* rel_out = out + (size_t)n_nodes * D;

  // ws layout
  char* ws = (char*)d_ws;
  size_t offX = 0;
  size_t offR = offX + (size_t)n_nodes * D * 4;
  size_t offCur = offR + (size_t)n_rel * D * 4;
  size_t offSums = offCur + (size_t)n_nodes * 4;
  size_t offPerm = offSums + 1024 * 4;
  size_t need = offPerm + (size_t)n_edges * 4;

  float* X = (float*)(ws + offX);
  float* R = (float*)(ws + offR);
  int* cursor = (int*)(ws + offCur);
  int* sums = (int*)(ws + offSums);
  int* perm = (int*)(ws + offPerm);

  // 1) R and rel_out
  rel_kernel<<<50, 256, 0, stream>>>(rel_emb, W_forward, W_rel, R, rel_out, n_rel);

  // 2) out = nf@Ws^T + bias ; X = nf@Wf^T  (two light passes)
  node_mm<<<2048, 256, 0, stream>>>(node_feat, W_self, bias, out, n_nodes);
  node_mm<<<2048, 256, 0, stream>>>(node_feat, W_forward, nullptr, X, n_nodes);

  if (ws_size >= need) {
    int nblk = (n_nodes + SCAN_CHUNK - 1) / SCAN_CHUNK;  // 98 for 100K
    k_zero<<<256, 256, 0, stream>>>(cursor, n_nodes + 1024);  // cursor+sums contiguous
    k_hist<<<1024, 256, 0, stream>>>(dst, direction, cursor, n_edges);
    k_sums<<<nblk, 256, 0, stream>>>(cursor, sums, n_nodes);
    k_scan_sums<<<1, 1024, 0, stream>>>(sums, nblk);
    k_scan_chunks<<<nblk, 256, 0, stream>>>(cursor, sums, n_nodes);
    k_scatter<<<1024, 256, 0, stream>>>(dst, direction, cursor, perm, n_edges);
    k_gather<<<2048, 256, 0, stream>>>(cursor, perm, src, etype, X, R, out, n_nodes);
  } else {
    edge_atomic<<<2048, 256, 0, stream>>>(src, dst, etype, direction, X, R, out,
                                          n_edges);
  }
}